// Round 4
// baseline (221.195 us; speedup 1.0000x reference)
//
#include <hip/hip_runtime.h>
#include <math.h>

// Problem constants (fixed shapes from setup_inputs)
#define BI 128
#define BT 128
#define RR 36
#define WW 50
#define DD 256
#define LAMB_INV 20.0f   // 1/0.05
#define EPSF 1e-6f

#define A_TILES 3        // ceil(36/16)
#define B_TILES 4        // ceil(50/16)
#define KSTEPS 8         // 256 / 32
#define A_SLOTS (BI * A_TILES * KSTEPS * 64)  // 196608 x 16B = 3 MiB
#define B_SLOTS (BT * B_TILES * KSTEPS * 64)  // 262144 x 16B = 4 MiB
// d_ws layout: [Ah | Al | Bh | Bl] = 2*(3+4) MiB = 14,680,064 bytes

#define CV_AT (BI * A_TILES)   // 384 A-tiles
#define CV_BT (BT * B_TILES)   // 512 B-tiles

typedef short  v8ss __attribute__((ext_vector_type(8)));
typedef __bf16 v8bf __attribute__((ext_vector_type(8)));
typedef float  v4f  __attribute__((ext_vector_type(4)));

// MFMA shim: tolerate either builtin operand type (v8bf16 or v8i16).
template <typename V>
__device__ __forceinline__ auto mfma_impl(V a, V b, v4f c, int)
    -> decltype(__builtin_amdgcn_mfma_f32_16x16x32_bf16(a, b, c, 0, 0, 0)) {
    return __builtin_amdgcn_mfma_f32_16x16x32_bf16(a, b, c, 0, 0, 0);
}
template <typename V>
__device__ __forceinline__ v4f mfma_impl(V a, V b, v4f c, long) {
    v8ss a2 = __builtin_bit_cast(v8ss, a);
    v8ss b2 = __builtin_bit_cast(v8ss, b);
    return __builtin_amdgcn_mfma_f32_16x16x32_bf16(a2, b2, c, 0, 0, 0);
}
__device__ __forceinline__ v4f mfma_bf16(v8bf a, v8bf b, v4f c) {
    return mfma_impl(a, b, c, 0);
}

// fp32 -> bf16 RNE split helpers (hi + lo representation)
__device__ __forceinline__ unsigned short f2bf(float x) {
    unsigned int u = __builtin_bit_cast(unsigned int, x);
    u += 0x7fffu + ((u >> 16) & 1u);
    return (unsigned short)(u >> 16);
}
__device__ __forceinline__ float bf2f(unsigned short b) {
    unsigned int u = ((unsigned int)b) << 16;
    return __builtin_bit_cast(float, u);
}

// fast reciprocal: v_rcp_f32 (~1 ulp) instead of the ~20-instr exact divide
__device__ __forceinline__ float fast_rcp(float x) {
    return __builtin_amdgcn_rcpf(x);
}

// DPP row_ror-based sum over each aligned 16-lane group (all lanes get sum)
template <int N>
__device__ __forceinline__ float dpp_ror_add(float x) {
    int xi = __builtin_bit_cast(int, x);
    int yi = __builtin_amdgcn_update_dpp(xi, xi, 0x120 | N, 0xF, 0xF, false);
    return x + __builtin_bit_cast(float, yi);
}
__device__ __forceinline__ float dpp_sum16(float x) {
    x = dpp_ror_add<1>(x);
    x = dpp_ror_add<2>(x);
    x = dpp_ror_add<4>(x);
    x = dpp_ror_add<8>(x);
    return x;
}

// ---------------------------------------------------------------------------
// Kernel 1 (rewritten): one block per 16-row output tile.
//   step 1: coalesced load of 16 rows x 256 floats into LDS
//   step 2: per-row inverse L2 norms (16 lanes/row, DPP reduce)
//   step 3: bf16 hi/lo split, COALESCED fragment stores (lane == slot)
// Pad rows write zeros so poisoned d_ws is fully initialized.
// ---------------------------------------------------------------------------
__global__ __launch_bounds__(256) void convert_kernel(
    const float* __restrict__ imgs, const float* __restrict__ caps,
    v8ss* __restrict__ Ah_g, v8ss* __restrict__ Al_g,
    v8ss* __restrict__ Bh_g, v8ss* __restrict__ Bl_g)
{
    __shared__ float raw[16][260];   // +4 pad: odd float4-stride, conflict-light
    __shared__ float invn[16];

    const int t = threadIdx.x;
    const int b = blockIdx.x;
    const bool isA = b < CV_AT;
    int grp, tile, nrows;
    const float* src;
    v8ss *Hg, *Lg;
    if (isA) {
        grp = b / A_TILES; tile = b - grp * A_TILES;
        src = imgs + (size_t)grp * RR * DD;
        nrows = RR; Hg = Ah_g; Lg = Al_g;
    } else {
        int bb = b - CV_AT;
        grp = bb / B_TILES; tile = bb - grp * B_TILES;
        src = caps + (size_t)grp * WW * DD;
        nrows = WW; Hg = Bh_g; Lg = Bl_g;
    }
    const size_t tbase = (size_t)b * (KSTEPS * 64) - (isA ? 0 : (size_t)CV_AT * KSTEPS * 64);
    const int r0 = tile << 4;

    // step 1: stage (rows >= nrows -> zeros)
    for (int f = t; f < 1024; f += 256) {
        const int row = f >> 6, c4 = f & 63;
        float4 v = make_float4(0.f, 0.f, 0.f, 0.f);
        const int r = r0 + row;
        if (r < nrows) v = *(const float4*)(src + (size_t)r * DD + c4 * 4);
        *(float4*)&raw[row][c4 * 4] = v;
    }
    __syncthreads();

    // step 2: inverse norms; 16 lanes per row, lane-interleaved reads
    {
        const int row = t >> 4, seg = t & 15;
        float ss = 0.f;
#pragma unroll
        for (int k = 0; k < 16; ++k) {
            float x = raw[row][k * 16 + seg];
            ss += x * x;
        }
        ss = dpp_sum16(ss);
        if (seg == 0) invn[row] = 1.0f / fmaxf(sqrtf(ss), 1e-8f);
    }
    __syncthreads();

    // step 3: split + coalesced stores (512 slots, 2 per thread)
    for (int u = t; u < KSTEPS * 64; u += 256) {
        const int ks = u >> 6, sl = u & 63;
        const int rr = sl & 15, kq = sl >> 4;
        const float inv = invn[rr];
        const float* p = &raw[rr][ks * 32 + kq * 8];
        float4 f0 = *(const float4*)p;
        float4 f1 = *(const float4*)(p + 4);
        float xs[8] = {f0.x, f0.y, f0.z, f0.w, f1.x, f1.y, f1.z, f1.w};
        v8ss h, l;
#pragma unroll
        for (int e = 0; e < 8; ++e) {
            float x = xs[e] * inv;
            unsigned short hb = f2bf(x);
            unsigned short lb = f2bf(x - bf2f(hb));
            h[e] = (short)hb; l[e] = (short)lb;
        }
        Hg[tbase + (size_t)ks * 64 + sl] = h;
        Lg[tbase + (size_t)ks * 64 + sl] = l;
    }
}

// ---------------------------------------------------------------------------
// Kernel 2: block = 4 waves = 1 i x 8 j (2 j-rounds per wave).
// A-fragments (hi+lo, all k) staged ONCE per block into LDS (<=48KB);
// B-fragments double-buffered from global (L2-resident). 3-pass split-bf16
// MFMA pruned by valid lengths. Sinkhorn fully in registers: row sums via
// DPP row_ror (lane groups of 16 == C-layout quad-rows), col sums via
// xor-shuffles 16/32, divides via v_rcp_f32.
// C/D layout: col = lane&15, row = (lane>>4)*4 + reg.
// ---------------------------------------------------------------------------
__global__ __launch_bounds__(256) void pair_kernel(
    const v8ss* __restrict__ Ah_g, const v8ss* __restrict__ Al_g,
    const v8ss* __restrict__ Bh_g, const v8ss* __restrict__ Bl_g,
    const int* __restrict__ img_lens, const int* __restrict__ cap_lens,
    float* __restrict__ out)
{
    __shared__ v8ss AhL[A_TILES * KSTEPS * 64];   // 24 KB
    __shared__ v8ss AlL[A_TILES * KSTEPS * 64];   // 24 KB

    const int tid  = threadIdx.x;
    const int lane = tid & 63;
    const int w    = tid >> 6;
    const int i    = blockIdx.x >> 4;
    const int j0   = (blockIdx.x & 15) << 3;

    const int nr = img_lens[i];
    const int Ma = (nr + 15) >> 4;

    // stage A (hi+lo) for this i: nslot <= 1536 16B-chunks, coalesced
    {
        const v8ss* AhG = Ah_g + (size_t)i * (A_TILES * KSTEPS * 64);
        const v8ss* AlG = Al_g + (size_t)i * (A_TILES * KSTEPS * 64);
        const int nslot = Ma * KSTEPS * 64;
        for (int s = tid; s < nslot; s += 256) {
            AhL[s] = AhG[s];
            AlL[s] = AlG[s];
        }
    }
    __syncthreads();

    const int cl = lane & 15;
    const int rq = (lane >> 4) << 2;
    const float inv_nr = 1.0f / (float)nr;

    for (int jj = 0; jj < 2; ++jj) {
        const int j  = j0 + (w << 1) + jj;
        const int nc = cap_lens[j];
        const int Na = (nc + 15) >> 4;
        const float inv_nc = 1.0f / (float)nc;

        const v8ss* Bh_b = Bh_g + (size_t)j * (B_TILES * KSTEPS * 64) + lane;
        const v8ss* Bl_b = Bl_g + (size_t)j * (B_TILES * KSTEPS * 64) + lane;

        v4f acc[3][4];
#pragma unroll
        for (int m = 0; m < 3; ++m)
#pragma unroll
            for (int n = 0; n < 4; ++n) acc[m][n] = (v4f){0.f, 0.f, 0.f, 0.f};

        v8bf bh[2][4], bl[2][4];
        auto load_B = [&](int ks, int buf) {
#pragma unroll
            for (int n = 0; n < 4; ++n) if (n < Na) {
                bh[buf][n] = __builtin_bit_cast(v8bf, Bh_b[(n * KSTEPS + ks) * 64]);
                bl[buf][n] = __builtin_bit_cast(v8bf, Bl_b[(n * KSTEPS + ks) * 64]);
            }
        };

        load_B(0, 0);
#pragma unroll
        for (int ks = 0; ks < KSTEPS; ++ks) {
            const int cur = ks & 1;
            if (ks + 1 < KSTEPS) load_B(ks + 1, cur ^ 1);
            v8bf ah[3], al[3];
#pragma unroll
            for (int m = 0; m < 3; ++m) if (m < Ma) {
                ah[m] = __builtin_bit_cast(v8bf, AhL[(m * KSTEPS + ks) * 64 + lane]);
                al[m] = __builtin_bit_cast(v8bf, AlL[(m * KSTEPS + ks) * 64 + lane]);
            }
#pragma unroll
            for (int n = 0; n < 4; ++n) if (n < Na)
#pragma unroll
                for (int m = 0; m < 3; ++m) if (m < Ma) {
                    acc[m][n] = mfma_bf16(ah[m], bh[cur][n], acc[m][n]);  // hi*hi
                    acc[m][n] = mfma_bf16(al[m], bh[cur][n], acc[m][n]);  // lo*hi
                    acc[m][n] = mfma_bf16(ah[m], bl[cur][n], acc[m][n]);  // hi*lo
                }
        }

        // ---- Sinkhorn, fully in registers ----
        float P[3][4][4];
        float tot = 0.f;
#pragma unroll
        for (int m = 0; m < 3; ++m) if (m < Ma)
#pragma unroll
            for (int n = 0; n < 4; ++n) if (n < Na)
#pragma unroll
                for (int q = 0; q < 4; ++q) {
                    const int row = (m << 4) + rq + q;
                    const int col = (n << 4) + cl;
                    float pv = 0.f;
                    if (row < nr && col < nc)
                        pv = __expf((acc[m][n][q] - 1.0f) * LAMB_INV);
                    P[m][n][q] = pv;
                    tot += pv;
                }
        tot = dpp_sum16(tot);
        tot += __shfl_xor(tot, 16, 64);
        tot += __shfl_xor(tot, 32, 64);
        {
            const float gsc = fast_rcp(tot + EPSF);
#pragma unroll
            for (int m = 0; m < 3; ++m) if (m < Ma)
#pragma unroll
                for (int n = 0; n < 4; ++n) if (n < Na)
#pragma unroll
                    for (int q = 0; q < 4; ++q) P[m][n][q] *= gsc;
        }

#pragma unroll
        for (int it = 0; it < 3; ++it) {
            // row update: u = rowsum + EPS ; P *= (1/nr)/u (invalid rows keep P=0)
#pragma unroll
            for (int m = 0; m < 3; ++m) if (m < Ma)
#pragma unroll
                for (int q = 0; q < 4; ++q) {
                    float rs = 0.f;
#pragma unroll
                    for (int n = 0; n < 4; ++n) if (n < Na) rs += P[m][n][q];
                    rs = dpp_sum16(rs);
                    const float rsc = inv_nr * fast_rcp(rs + EPSF);
#pragma unroll
                    for (int n = 0; n < 4; ++n) if (n < Na) P[m][n][q] *= rsc;
                }
            // col update
#pragma unroll
            for (int n = 0; n < 4; ++n) if (n < Na) {
                float cs = 0.f;
#pragma unroll
                for (int m = 0; m < 3; ++m) if (m < Ma)
#pragma unroll
                    for (int q = 0; q < 4; ++q) cs += P[m][n][q];
                cs += __shfl_xor(cs, 16, 64);
                cs += __shfl_xor(cs, 32, 64);
                const float csc = inv_nc * fast_rcp(cs + EPSF);
#pragma unroll
                for (int m = 0; m < 3; ++m) if (m < Ma)
#pragma unroll
                    for (int q = 0; q < 4; ++q) P[m][n][q] *= csc;
            }
        }

        // ---- output: sum(S * P) ----
        float osum = 0.f;
#pragma unroll
        for (int m = 0; m < 3; ++m) if (m < Ma)
#pragma unroll
            for (int n = 0; n < 4; ++n) if (n < Na)
#pragma unroll
                for (int q = 0; q < 4; ++q) osum += acc[m][n][q] * P[m][n][q];
        osum = dpp_sum16(osum);
        osum += __shfl_xor(osum, 16, 64);
        osum += __shfl_xor(osum, 32, 64);
        if (lane == 0) out[i * BT + j] = osum;
    }
}

extern "C" void kernel_launch(void* const* d_in, const int* in_sizes, int n_in,
                              void* d_out, int out_size, void* d_ws, size_t ws_size,
                              hipStream_t stream) {
    const float* imgs     = (const float*)d_in[0];
    const float* caps     = (const float*)d_in[1];
    const int*   img_lens = (const int*)d_in[2];
    const int*   cap_lens = (const int*)d_in[3];
    float* out = (float*)d_out;

    // workspace layout (14,680,064 bytes total)
    v8ss* Ah_g = (v8ss*)d_ws;
    v8ss* Al_g = Ah_g + A_SLOTS;
    v8ss* Bh_g = Al_g + A_SLOTS;
    v8ss* Bl_g = Bh_g + B_SLOTS;

    hipLaunchKernelGGL(convert_kernel, dim3(CV_AT + CV_BT), dim3(256), 0, stream,
                       imgs, caps, Ah_g, Al_g, Bh_g, Bl_g);
    hipLaunchKernelGGL(pair_kernel, dim3(BI * 16), dim3(256), 0, stream,
                       Ah_g, Al_g, Bh_g, Bl_g, img_lens, cap_lens, out);
}

// Round 5
// 145.607 us; speedup vs baseline: 1.5191x; 1.5191x over previous
//
#include <hip/hip_runtime.h>
#include <math.h>

// Problem constants (fixed shapes from setup_inputs)
#define BI 128
#define BT 128
#define RR 36
#define WW 50
#define DD 256
#define LAMB_INV 20.0f   // 1/0.05
#define EPSF 1e-6f

#define A_TILES 3        // ceil(36/16)
#define B_TILES 4        // ceil(50/16)
#define KSTEPS 8         // 256 / 32
#define A_SLOTS (BI * A_TILES * KSTEPS * 64)  // 196608 slots x 16B = 3 MiB
#define B_SLOTS (BT * B_TILES * KSTEPS * 64)  // 262144 slots x 16B = 4 MiB
// d_ws layout: [Ah | Al | Bh] (f16 fragments) = 3+3+4 MiB = 10,485,760 bytes

#define CV_AT (BI * A_TILES)   // 384 A-tiles
#define CV_BT (BT * B_TILES)   // 512 B-tiles

typedef short     v8ss __attribute__((ext_vector_type(8)));
typedef _Float16  v8hf __attribute__((ext_vector_type(8)));
typedef float     v4f  __attribute__((ext_vector_type(4)));

// MFMA shim: tolerate either builtin operand type (v8 half or v8 short).
template <typename V>
__device__ __forceinline__ auto mfma_impl(V a, V b, v4f c, int)
    -> decltype(__builtin_amdgcn_mfma_f32_16x16x32_f16(a, b, c, 0, 0, 0)) {
    return __builtin_amdgcn_mfma_f32_16x16x32_f16(a, b, c, 0, 0, 0);
}
template <typename V>
__device__ __forceinline__ v4f mfma_impl(V a, V b, v4f c, long) {
    v8ss a2 = __builtin_bit_cast(v8ss, a);
    v8ss b2 = __builtin_bit_cast(v8ss, b);
    return __builtin_amdgcn_mfma_f32_16x16x32_f16(a2, b2, c, 0, 0, 0);
}
__device__ __forceinline__ v4f mfma_f16(v8hf a, v8hf b, v4f c) {
    return mfma_impl(a, b, c, 0);
}

// fast reciprocal: v_rcp_f32 (~1 ulp) instead of the ~20-instr exact divide
__device__ __forceinline__ float fast_rcp(float x) {
    return __builtin_amdgcn_rcpf(x);
}

// DPP row_ror-based sum over each aligned 16-lane group (all lanes get sum)
template <int N>
__device__ __forceinline__ float dpp_ror_add(float x) {
    int xi = __builtin_bit_cast(int, x);
    int yi = __builtin_amdgcn_update_dpp(xi, xi, 0x120 | N, 0xF, 0xF, false);
    return x + __builtin_bit_cast(float, yi);
}
__device__ __forceinline__ float dpp_sum16(float x) {
    x = dpp_ror_add<1>(x);
    x = dpp_ror_add<2>(x);
    x = dpp_ror_add<4>(x);
    x = dpp_ror_add<8>(x);
    return x;
}

// ---------------------------------------------------------------------------
// Kernel 1: one block per 16-row output tile.
//   step 1: coalesced load of 16 rows x 256 floats into LDS
//   step 2: per-row inverse L2 norms (16 lanes/row, DPP reduce)
//   step 3: f16 split (A: hi+lo, B: hi only), COALESCED fragment stores.
// Pad rows write zeros so poisoned d_ws is fully initialized.
// ---------------------------------------------------------------------------
__global__ __launch_bounds__(256) void convert_kernel(
    const float* __restrict__ imgs, const float* __restrict__ caps,
    v8ss* __restrict__ Ah_g, v8ss* __restrict__ Al_g,
    v8ss* __restrict__ Bh_g)
{
    __shared__ float raw[16][260];   // +4 pad: odd float4-stride, conflict-light
    __shared__ float invn[16];

    const int t = threadIdx.x;
    const int b = blockIdx.x;
    const bool isA = b < CV_AT;
    int grp, tile, nrows;
    const float* src;
    if (isA) {
        grp = b / A_TILES; tile = b - grp * A_TILES;
        src = imgs + (size_t)grp * RR * DD;
        nrows = RR;
    } else {
        int bb = b - CV_AT;
        grp = bb / B_TILES; tile = bb - grp * B_TILES;
        src = caps + (size_t)grp * WW * DD;
        nrows = WW;
    }
    const size_t tbase = isA ? (size_t)b * (KSTEPS * 64)
                             : (size_t)(b - CV_AT) * (KSTEPS * 64);
    const int r0 = tile << 4;

    // step 1: stage (rows >= nrows -> zeros)
    for (int f = t; f < 1024; f += 256) {
        const int row = f >> 6, c4 = f & 63;
        float4 v = make_float4(0.f, 0.f, 0.f, 0.f);
        const int r = r0 + row;
        if (r < nrows) v = *(const float4*)(src + (size_t)r * DD + c4 * 4);
        *(float4*)&raw[row][c4 * 4] = v;
    }
    __syncthreads();

    // step 2: inverse norms; 16 lanes per row
    {
        const int row = t >> 4, seg = t & 15;
        float ss = 0.f;
#pragma unroll
        for (int k = 0; k < 16; ++k) {
            float x = raw[row][k * 16 + seg];
            ss += x * x;
        }
        ss = dpp_sum16(ss);
        if (seg == 0) invn[row] = 1.0f / fmaxf(sqrtf(ss), 1e-8f);
    }
    __syncthreads();

    // step 3: split + coalesced stores (512 slots, 2 per thread)
    for (int u = t; u < KSTEPS * 64; u += 256) {
        const int ks = u >> 6, sl = u & 63;
        const int rr = sl & 15, kq = sl >> 4;
        const float inv = invn[rr];
        const float* p = &raw[rr][ks * 32 + kq * 8];
        float4 f0 = *(const float4*)p;
        float4 f1 = *(const float4*)(p + 4);
        float xs[8] = {f0.x, f0.y, f0.z, f0.w, f1.x, f1.y, f1.z, f1.w};
        v8hf h, l;
#pragma unroll
        for (int e = 0; e < 8; ++e) {
            float x = xs[e] * inv;
            _Float16 hh = (_Float16)x;           // RNE f16
            h[e] = hh;
            l[e] = (_Float16)(x - (float)hh);    // residual
        }
        if (isA) {
            Ah_g[tbase + (size_t)ks * 64 + sl] = __builtin_bit_cast(v8ss, h);
            Al_g[tbase + (size_t)ks * 64 + sl] = __builtin_bit_cast(v8ss, l);
        } else {
            Bh_g[tbase + (size_t)ks * 64 + sl] = __builtin_bit_cast(v8ss, h);
        }
    }
}

// ---------------------------------------------------------------------------
// Kernel 2: one wave per (i,j) pair; 4 waves/block share i. No LDS.
// f16 2-pass MFMA (S = Ah*Bh + Al*Bh; B error 2^-12 negligible after x20 exp),
// register double-buffered (10 fragments/kstep = 80 VGPR, fits real prefetch),
// tiles pruned by valid lengths.
// Sinkhorn via u/v factorization: P = P0 o (u x v); only the 16 factor regs
// are updated per iteration. Row sums via DPP row_ror (16-lane groups = C/D
// layout rows), col sums via xor-shuffles 16/32, divides via v_rcp_f32.
// C/D layout: col = lane&15, row = (lane>>4)*4 + reg.
// ---------------------------------------------------------------------------
__global__ __launch_bounds__(256) void pair_kernel(
    const v8ss* __restrict__ Ah_g, const v8ss* __restrict__ Al_g,
    const v8ss* __restrict__ Bh_g,
    const int* __restrict__ img_lens, const int* __restrict__ cap_lens,
    float* __restrict__ out)
{
    const int tid  = threadIdx.x;
    const int lane = tid & 63;
    const int w    = tid >> 6;
    const int i    = blockIdx.x >> 5;
    const int j    = ((blockIdx.x & 31) << 2) + w;

    const int nr = img_lens[i];
    const int nc = cap_lens[j];
    const int Ma = (nr + 15) >> 4;
    const int Na = (nc + 15) >> 4;

    const v8ss* Ah_b = Ah_g + (size_t)i * (A_TILES * KSTEPS * 64) + lane;
    const v8ss* Al_b = Al_g + (size_t)i * (A_TILES * KSTEPS * 64) + lane;
    const v8ss* Bh_b = Bh_g + (size_t)j * (B_TILES * KSTEPS * 64) + lane;

    v4f acc[3][4];
#pragma unroll
    for (int m = 0; m < 3; ++m)
#pragma unroll
        for (int n = 0; n < 4; ++n) acc[m][n] = (v4f){0.f, 0.f, 0.f, 0.f};

    v8hf ah[2][3], al[2][3], bh[2][4];
    auto load_stage = [&](int ks, int buf) {
#pragma unroll
        for (int m = 0; m < 3; ++m) if (m < Ma) {
            ah[buf][m] = __builtin_bit_cast(v8hf, Ah_b[(m * KSTEPS + ks) * 64]);
            al[buf][m] = __builtin_bit_cast(v8hf, Al_b[(m * KSTEPS + ks) * 64]);
        }
#pragma unroll
        for (int n = 0; n < 4; ++n) if (n < Na)
            bh[buf][n] = __builtin_bit_cast(v8hf, Bh_b[(n * KSTEPS + ks) * 64]);
    };

    load_stage(0, 0);
#pragma unroll
    for (int ks = 0; ks < KSTEPS; ++ks) {
        const int cur = ks & 1;
        if (ks + 1 < KSTEPS) load_stage(ks + 1, cur ^ 1);
#pragma unroll
        for (int n = 0; n < 4; ++n) if (n < Na)
#pragma unroll
            for (int m = 0; m < 3; ++m) if (m < Ma) {
                acc[m][n] = mfma_f16(ah[cur][m], bh[cur][n], acc[m][n]);  // hi*hi
                acc[m][n] = mfma_f16(al[cur][m], bh[cur][n], acc[m][n]);  // lo*hi
            }
    }

    // ---- Sinkhorn via u/v factorization ----
    const int cl = lane & 15;
    const int rq = (lane >> 4) << 2;
    const float inv_nr = 1.0f / (float)nr;
    const float inv_nc = 1.0f / (float)nc;

    float P0[3][4][4];
    float tot = 0.f;
#pragma unroll
    for (int m = 0; m < 3; ++m) if (m < Ma)
#pragma unroll
        for (int n = 0; n < 4; ++n) if (n < Na)
#pragma unroll
            for (int q = 0; q < 4; ++q) {
                const int row = (m << 4) + rq + q;
                const int col = (n << 4) + cl;
                float pv = 0.f;
                if (row < nr && col < nc)
                    pv = __expf((acc[m][n][q] - 1.0f) * LAMB_INV);
                P0[m][n][q] = pv;
                tot += pv;
            }
    tot = dpp_sum16(tot);
    tot += __shfl_xor(tot, 16, 64);
    tot += __shfl_xor(tot, 32, 64);
    const float gsc = fast_rcp(tot + EPSF);

    float u[3][4], v[4];
#pragma unroll
    for (int m = 0; m < 3; ++m)
#pragma unroll
        for (int q = 0; q < 4; ++q) u[m][q] = gsc;   // rows with P0=0 harmless
#pragma unroll
    for (int n = 0; n < 4; ++n) v[n] = 1.0f;

#pragma unroll
    for (int it = 0; it < 3; ++it) {
        // row update: t = u[r]*sum_c(P0*v); u *= (1/nr)*rcp(t+EPS)
#pragma unroll
        for (int m = 0; m < 3; ++m) if (m < Ma)
#pragma unroll
            for (int q = 0; q < 4; ++q) {
                float d = 0.f;
#pragma unroll
                for (int n = 0; n < 4; ++n) if (n < Na)
                    d = fmaf(P0[m][n][q], v[n], d);
                d = dpp_sum16(d);
                const float t = u[m][q] * d;
                u[m][q] *= inv_nr * fast_rcp(t + EPSF);
            }
        // col update: t = v[c]*sum_r(P0*u); v *= (1/nc)*rcp(t+EPS)
#pragma unroll
        for (int n = 0; n < 4; ++n) if (n < Na) {
            float e = 0.f;
#pragma unroll
            for (int m = 0; m < 3; ++m) if (m < Ma)
#pragma unroll
                for (int q = 0; q < 4; ++q)
                    e = fmaf(P0[m][n][q], u[m][q], e);
            e += __shfl_xor(e, 16, 64);
            e += __shfl_xor(e, 32, 64);
            const float t = v[n] * e;
            v[n] *= inv_nc * fast_rcp(t + EPSF);
        }
    }

    // ---- output: sum(S * P0 * u * v) ----
    float osum = 0.f;
#pragma unroll
    for (int m = 0; m < 3; ++m) if (m < Ma)
#pragma unroll
        for (int n = 0; n < 4; ++n) if (n < Na)
#pragma unroll
            for (int q = 0; q < 4; ++q)
                osum = fmaf(acc[m][n][q], P0[m][n][q] * u[m][q] * v[n], osum);
    osum = dpp_sum16(osum);
    osum += __shfl_xor(osum, 16, 64);
    osum += __shfl_xor(osum, 32, 64);
    if (lane == 0) out[i * BT + j] = osum;
}

extern "C" void kernel_launch(void* const* d_in, const int* in_sizes, int n_in,
                              void* d_out, int out_size, void* d_ws, size_t ws_size,
                              hipStream_t stream) {
    const float* imgs     = (const float*)d_in[0];
    const float* caps     = (const float*)d_in[1];
    const int*   img_lens = (const int*)d_in[2];
    const int*   cap_lens = (const int*)d_in[3];
    float* out = (float*)d_out;

    // workspace layout (10,485,760 bytes total)
    v8ss* Ah_g = (v8ss*)d_ws;
    v8ss* Al_g = Ah_g + A_SLOTS;
    v8ss* Bh_g = Al_g + A_SLOTS;

    hipLaunchKernelGGL(convert_kernel, dim3(CV_AT + CV_BT), dim3(256), 0, stream,
                       imgs, caps, Ah_g, Al_g, Bh_g);
    hipLaunchKernelGGL(pair_kernel, dim3(BI * 32), dim3(256), 0, stream,
                       Ah_g, Al_g, Bh_g, img_lens, cap_lens, out);
}

// Round 6
// 139.385 us; speedup vs baseline: 1.5869x; 1.0446x over previous
//
#include <hip/hip_runtime.h>
#include <math.h>

// Problem constants (fixed shapes from setup_inputs)
#define BI 128
#define BT 128
#define RR 36
#define WW 50
#define DD 256
#define EPSF 1e-6f
// exp((s-1)/0.05) = exp2(s*C1 + C0), C1 = 20*log2(e), C0 = -C1
#define EXP2_C1 28.85390081777927f
#define EXP2_C0 (-28.85390081777927f)

#define A_TILES 3        // ceil(36/16)
#define B_TILES 4        // ceil(50/16)
#define KSTEPS 8         // 256 / 32
#define A_SLOTS (BI * A_TILES * KSTEPS * 64)  // 196608 slots x 16B = 3 MiB
#define B_SLOTS (BT * B_TILES * KSTEPS * 64)  // 262144 slots x 16B = 4 MiB
// d_ws layout: [Ah | Al | Bh] (f16 fragments) = 3+3+4 MiB = 10,485,760 bytes

#define CV_AT (BI * A_TILES)   // 384 A-tiles
#define CV_BT (BT * B_TILES)   // 512 B-tiles

typedef short     v8ss __attribute__((ext_vector_type(8)));
typedef _Float16  v8hf __attribute__((ext_vector_type(8)));
typedef float     v4f  __attribute__((ext_vector_type(4)));

// MFMA shim: tolerate either builtin operand type (v8 half or v8 short).
template <typename V>
__device__ __forceinline__ auto mfma_impl(V a, V b, v4f c, int)
    -> decltype(__builtin_amdgcn_mfma_f32_16x16x32_f16(a, b, c, 0, 0, 0)) {
    return __builtin_amdgcn_mfma_f32_16x16x32_f16(a, b, c, 0, 0, 0);
}
template <typename V>
__device__ __forceinline__ v4f mfma_impl(V a, V b, v4f c, long) {
    v8ss a2 = __builtin_bit_cast(v8ss, a);
    v8ss b2 = __builtin_bit_cast(v8ss, b);
    return __builtin_amdgcn_mfma_f32_16x16x32_f16(a2, b2, c, 0, 0, 0);
}
__device__ __forceinline__ v4f mfma_f16(v8hf a, v8hf b, v4f c) {
    return mfma_impl(a, b, c, 0);
}

// fast reciprocal: v_rcp_f32 (~1 ulp) instead of the ~20-instr exact divide
__device__ __forceinline__ float fast_rcp(float x) {
    return __builtin_amdgcn_rcpf(x);
}
// exp2 via v_exp_f32
__device__ __forceinline__ float fast_exp2(float x) {
    return __builtin_amdgcn_exp2f(x);
}

// DPP row_ror-based sum over each aligned 16-lane group (all lanes get sum)
template <int N>
__device__ __forceinline__ float dpp_ror_add(float x) {
    int xi = __builtin_bit_cast(int, x);
    int yi = __builtin_amdgcn_update_dpp(xi, xi, 0x120 | N, 0xF, 0xF, false);
    return x + __builtin_bit_cast(float, yi);
}
__device__ __forceinline__ float dpp_sum16(float x) {
    x = dpp_ror_add<1>(x);
    x = dpp_ror_add<2>(x);
    x = dpp_ror_add<4>(x);
    x = dpp_ror_add<8>(x);
    return x;
}

// ---------------------------------------------------------------------------
// Kernel 1: one block per 16-row output tile.
//   step 1: coalesced load of 16 rows x 256 floats into LDS
//   step 2: per-row inverse L2 norms (16 lanes/row, DPP reduce)
//   step 3: f16 split (A: hi+lo, B: hi only), COALESCED fragment stores.
// Pad rows write zeros so poisoned d_ws is fully initialized.
// ---------------------------------------------------------------------------
__global__ __launch_bounds__(256) void convert_kernel(
    const float* __restrict__ imgs, const float* __restrict__ caps,
    v8ss* __restrict__ Ah_g, v8ss* __restrict__ Al_g,
    v8ss* __restrict__ Bh_g)
{
    __shared__ float raw[16][260];   // +4 pad: odd float4-stride, conflict-light
    __shared__ float invn[16];

    const int t = threadIdx.x;
    const int b = blockIdx.x;
    const bool isA = b < CV_AT;
    int grp, tile, nrows;
    const float* src;
    if (isA) {
        grp = b / A_TILES; tile = b - grp * A_TILES;
        src = imgs + (size_t)grp * RR * DD;
        nrows = RR;
    } else {
        int bb = b - CV_AT;
        grp = bb / B_TILES; tile = bb - grp * B_TILES;
        src = caps + (size_t)grp * WW * DD;
        nrows = WW;
    }
    const size_t tbase = isA ? (size_t)b * (KSTEPS * 64)
                             : (size_t)(b - CV_AT) * (KSTEPS * 64);
    const int r0 = tile << 4;

    // step 1: stage (rows >= nrows -> zeros)
    for (int f = t; f < 1024; f += 256) {
        const int row = f >> 6, c4 = f & 63;
        float4 v = make_float4(0.f, 0.f, 0.f, 0.f);
        const int r = r0 + row;
        if (r < nrows) v = *(const float4*)(src + (size_t)r * DD + c4 * 4);
        *(float4*)&raw[row][c4 * 4] = v;
    }
    __syncthreads();

    // step 2: inverse norms; 16 lanes per row
    {
        const int row = t >> 4, seg = t & 15;
        float ss = 0.f;
#pragma unroll
        for (int k = 0; k < 16; ++k) {
            float x = raw[row][k * 16 + seg];
            ss += x * x;
        }
        ss = dpp_sum16(ss);
        if (seg == 0) invn[row] = 1.0f / fmaxf(sqrtf(ss), 1e-8f);
    }
    __syncthreads();

    // step 3: split + coalesced stores (512 slots, 2 per thread)
    for (int u = t; u < KSTEPS * 64; u += 256) {
        const int ks = u >> 6, sl = u & 63;
        const int rr = sl & 15, kq = sl >> 4;
        const float inv = invn[rr];
        const float* p = &raw[rr][ks * 32 + kq * 8];
        float4 f0 = *(const float4*)p;
        float4 f1 = *(const float4*)(p + 4);
        float xs[8] = {f0.x, f0.y, f0.z, f0.w, f1.x, f1.y, f1.z, f1.w};
        v8hf h, l;
#pragma unroll
        for (int e = 0; e < 8; ++e) {
            float x = xs[e] * inv;
            _Float16 hh = (_Float16)x;           // RNE f16
            h[e] = hh;
            l[e] = (_Float16)(x - (float)hh);    // residual
        }
        if (isA) {
            Ah_g[tbase + (size_t)ks * 64 + sl] = __builtin_bit_cast(v8ss, h);
            Al_g[tbase + (size_t)ks * 64 + sl] = __builtin_bit_cast(v8ss, l);
        } else {
            Bh_g[tbase + (size_t)ks * 64 + sl] = __builtin_bit_cast(v8ss, h);
        }
    }
}

// ---------------------------------------------------------------------------
// Kernel 2: ONE WAVE = ONE BLOCK = ONE (i,j) PAIR. 16384 blocks of 64
// threads: no intra-block co-retirement coupling (R5 showed 256-thread
// blocks held CU slots until the slowest of 4 heterogeneous pairs retired),
// finer scheduler packing, no LDS, no barriers.
// f16 2-pass MFMA (S = Ah*Bh + Al*Bh), register double-buffered, tiles
// pruned by valid lengths. Sinkhorn via u/v factorization on P0 = exp-part:
// row sums via DPP row_ror (16-lane groups = C/D rows), col sums via
// xor-shuffles 16/32, divides via v_rcp_f32, exp folded to one fma + v_exp.
// C/D layout: col = lane&15, row = (lane>>4)*4 + reg.
// ---------------------------------------------------------------------------
__global__ __launch_bounds__(64) void pair_kernel(
    const v8ss* __restrict__ Ah_g, const v8ss* __restrict__ Al_g,
    const v8ss* __restrict__ Bh_g,
    const int* __restrict__ img_lens, const int* __restrict__ cap_lens,
    float* __restrict__ out)
{
    const int lane = threadIdx.x;
    const int i    = blockIdx.x >> 7;   // 128 consecutive blocks share i (L2 reuse)
    const int j    = blockIdx.x & 127;

    const int nr = img_lens[i];
    const int nc = cap_lens[j];
    const int Ma = (nr + 15) >> 4;
    const int Na = (nc + 15) >> 4;

    const v8ss* Ah_b = Ah_g + (size_t)i * (A_TILES * KSTEPS * 64) + lane;
    const v8ss* Al_b = Al_g + (size_t)i * (A_TILES * KSTEPS * 64) + lane;
    const v8ss* Bh_b = Bh_g + (size_t)j * (B_TILES * KSTEPS * 64) + lane;

    v4f acc[3][4];
#pragma unroll
    for (int m = 0; m < 3; ++m)
#pragma unroll
        for (int n = 0; n < 4; ++n) acc[m][n] = (v4f){0.f, 0.f, 0.f, 0.f};

    v8hf ah[2][3], al[2][3], bh[2][4];
    auto load_stage = [&](int ks, int buf) {
#pragma unroll
        for (int m = 0; m < 3; ++m) if (m < Ma) {
            ah[buf][m] = __builtin_bit_cast(v8hf, Ah_b[(m * KSTEPS + ks) * 64]);
            al[buf][m] = __builtin_bit_cast(v8hf, Al_b[(m * KSTEPS + ks) * 64]);
        }
#pragma unroll
        for (int n = 0; n < 4; ++n) if (n < Na)
            bh[buf][n] = __builtin_bit_cast(v8hf, Bh_b[(n * KSTEPS + ks) * 64]);
    };

    load_stage(0, 0);
#pragma unroll
    for (int ks = 0; ks < KSTEPS; ++ks) {
        const int cur = ks & 1;
        if (ks + 1 < KSTEPS) load_stage(ks + 1, cur ^ 1);
#pragma unroll
        for (int n = 0; n < 4; ++n) if (n < Na)
#pragma unroll
            for (int m = 0; m < 3; ++m) if (m < Ma) {
                acc[m][n] = mfma_f16(ah[cur][m], bh[cur][n], acc[m][n]);  // hi*hi
                acc[m][n] = mfma_f16(al[cur][m], bh[cur][n], acc[m][n]);  // lo*hi
            }
    }

    // ---- Sinkhorn via u/v factorization ----
    const int cl = lane & 15;
    const int rq = (lane >> 4) << 2;
    const float inv_nr = 1.0f / (float)nr;
    const float inv_nc = 1.0f / (float)nc;

    float P0[3][4][4];
    float tot = 0.f;
#pragma unroll
    for (int m = 0; m < 3; ++m) if (m < Ma)
#pragma unroll
        for (int n = 0; n < 4; ++n) if (n < Na)
#pragma unroll
            for (int q = 0; q < 4; ++q) {
                const int row = (m << 4) + rq + q;
                const int col = (n << 4) + cl;
                float pv = 0.f;
                if (row < nr && col < nc)
                    pv = fast_exp2(fmaf(acc[m][n][q], EXP2_C1, EXP2_C0));
                P0[m][n][q] = pv;
                tot += pv;
            }
    tot = dpp_sum16(tot);
    tot += __shfl_xor(tot, 16, 64);
    tot += __shfl_xor(tot, 32, 64);
    const float gsc = fast_rcp(tot + EPSF);

    float u[3][4], v[4];
#pragma unroll
    for (int m = 0; m < 3; ++m)
#pragma unroll
        for (int q = 0; q < 4; ++q) u[m][q] = gsc;   // rows with P0=0 harmless
#pragma unroll
    for (int n = 0; n < 4; ++n) v[n] = 1.0f;

#pragma unroll
    for (int it = 0; it < 3; ++it) {
        // row update: t = u[r]*sum_c(P0*v); u *= (1/nr)*rcp(t+EPS)
#pragma unroll
        for (int m = 0; m < 3; ++m) if (m < Ma)
#pragma unroll
            for (int q = 0; q < 4; ++q) {
                float d = 0.f;
#pragma unroll
                for (int n = 0; n < 4; ++n) if (n < Na)
                    d = fmaf(P0[m][n][q], v[n], d);
                d = dpp_sum16(d);
                const float t = fmaf(u[m][q], d, EPSF);
                u[m][q] *= inv_nr * fast_rcp(t);
            }
        // col update: t = v[c]*sum_r(P0*u); v *= (1/nc)*rcp(t+EPS)
#pragma unroll
        for (int n = 0; n < 4; ++n) if (n < Na) {
            float e = 0.f;
#pragma unroll
            for (int m = 0; m < 3; ++m) if (m < Ma)
#pragma unroll
                for (int q = 0; q < 4; ++q)
                    e = fmaf(P0[m][n][q], u[m][q], e);
            e += __shfl_xor(e, 16, 64);
            e += __shfl_xor(e, 32, 64);
            const float t = fmaf(v[n], e, EPSF);
            v[n] *= inv_nc * fast_rcp(t);
        }
    }

    // ---- output: sum(S * P0 * u * v) ----
    float osum = 0.f;
#pragma unroll
    for (int m = 0; m < 3; ++m) if (m < Ma)
#pragma unroll
        for (int n = 0; n < 4; ++n) if (n < Na)
#pragma unroll
            for (int q = 0; q < 4; ++q)
                osum = fmaf(acc[m][n][q], P0[m][n][q] * u[m][q] * v[n], osum);
    osum = dpp_sum16(osum);
    osum += __shfl_xor(osum, 16, 64);
    osum += __shfl_xor(osum, 32, 64);
    if (lane == 0) out[i * BT + j] = osum;
}

extern "C" void kernel_launch(void* const* d_in, const int* in_sizes, int n_in,
                              void* d_out, int out_size, void* d_ws, size_t ws_size,
                              hipStream_t stream) {
    const float* imgs     = (const float*)d_in[0];
    const float* caps     = (const float*)d_in[1];
    const int*   img_lens = (const int*)d_in[2];
    const int*   cap_lens = (const int*)d_in[3];
    float* out = (float*)d_out;

    // workspace layout (10,485,760 bytes total)
    v8ss* Ah_g = (v8ss*)d_ws;
    v8ss* Al_g = Ah_g + A_SLOTS;
    v8ss* Bh_g = Al_g + A_SLOTS;

    hipLaunchKernelGGL(convert_kernel, dim3(CV_AT + CV_BT), dim3(256), 0, stream,
                       imgs, caps, Ah_g, Al_g, Bh_g);
    hipLaunchKernelGGL(pair_kernel, dim3(BI * BT), dim3(64), 0, stream,
                       Ah_g, Al_g, Bh_g, img_lens, cap_lens, out);
}

// Round 7
// 110.993 us; speedup vs baseline: 1.9929x; 1.2558x over previous
//
#include <hip/hip_runtime.h>
#include <math.h>

// Problem constants (fixed shapes from setup_inputs)
#define BI 128
#define BT 128
#define RR 36
#define WW 50
#define DD 256
#define EPSF 1e-6f
// exp((s-1)/0.05) = exp2(s*C1 + C0), C1 = 20*log2(e), C0 = -C1
#define EXP2_C1 28.85390081777927f
#define EXP2_C0 (-28.85390081777927f)

#define A_TILES 3        // ceil(36/16)
#define B_TILES 4        // ceil(50/16)
#define KSTEPS 8         // 256 / 32
#define A_SLOTS (BI * A_TILES * KSTEPS * 64)  // 196608 slots x 16B = 3 MiB
#define B_SLOTS (BT * B_TILES * KSTEPS * 64)  // 262144 slots x 16B = 4 MiB
// d_ws layout: [Ah | Bh] (f16 fragments) = 3+4 MiB = 7,340,032 bytes

#define CV_AT (BI * A_TILES)   // 384 A-tiles
#define CV_BT (BT * B_TILES)   // 512 B-tiles

typedef short     v8ss __attribute__((ext_vector_type(8)));
typedef _Float16  v8hf __attribute__((ext_vector_type(8)));
typedef float     v4f  __attribute__((ext_vector_type(4)));

// MFMA shim: tolerate either builtin operand type (v8 half or v8 short).
template <typename V>
__device__ __forceinline__ auto mfma_impl(V a, V b, v4f c, int)
    -> decltype(__builtin_amdgcn_mfma_f32_16x16x32_f16(a, b, c, 0, 0, 0)) {
    return __builtin_amdgcn_mfma_f32_16x16x32_f16(a, b, c, 0, 0, 0);
}
template <typename V>
__device__ __forceinline__ v4f mfma_impl(V a, V b, v4f c, long) {
    v8ss a2 = __builtin_bit_cast(v8ss, a);
    v8ss b2 = __builtin_bit_cast(v8ss, b);
    return __builtin_amdgcn_mfma_f32_16x16x32_f16(a2, b2, c, 0, 0, 0);
}
__device__ __forceinline__ v4f mfma_f16(v8hf a, v8hf b, v4f c) {
    return mfma_impl(a, b, c, 0);
}

// fast reciprocal: v_rcp_f32 (~1 ulp) instead of the ~20-instr exact divide
__device__ __forceinline__ float fast_rcp(float x) {
    return __builtin_amdgcn_rcpf(x);
}
// exp2 via v_exp_f32
__device__ __forceinline__ float fast_exp2(float x) {
    return __builtin_amdgcn_exp2f(x);
}

// DPP row_ror-based sum over each aligned 16-lane group (all lanes get sum)
template <int N>
__device__ __forceinline__ float dpp_ror_add(float x) {
    int xi = __builtin_bit_cast(int, x);
    int yi = __builtin_amdgcn_update_dpp(xi, xi, 0x120 | N, 0xF, 0xF, false);
    return x + __builtin_bit_cast(float, yi);
}
__device__ __forceinline__ float dpp_sum16(float x) {
    x = dpp_ror_add<1>(x);
    x = dpp_ror_add<2>(x);
    x = dpp_ror_add<4>(x);
    x = dpp_ror_add<8>(x);
    return x;
}

// ---------------------------------------------------------------------------
// Kernel 1: one block per 16-row output tile.
//   step 1: coalesced load of 16 rows x 256 floats into LDS
//   step 2: per-row inverse L2 norms (16 lanes/row, DPP reduce)
//   step 3: f16 convert (single hi value per element), COALESCED stores.
// Pad rows write zeros so poisoned d_ws is fully initialized.
// ---------------------------------------------------------------------------
__global__ __launch_bounds__(256) void convert_kernel(
    const float* __restrict__ imgs, const float* __restrict__ caps,
    v8ss* __restrict__ Ah_g, v8ss* __restrict__ Bh_g)
{
    __shared__ float raw[16][260];   // +4 pad: odd float4-stride, conflict-light
    __shared__ float invn[16];

    const int t = threadIdx.x;
    const int b = blockIdx.x;
    const bool isA = b < CV_AT;
    int grp, tile, nrows;
    const float* src;
    if (isA) {
        grp = b / A_TILES; tile = b - grp * A_TILES;
        src = imgs + (size_t)grp * RR * DD;
        nrows = RR;
    } else {
        int bb = b - CV_AT;
        grp = bb / B_TILES; tile = bb - grp * B_TILES;
        src = caps + (size_t)grp * WW * DD;
        nrows = WW;
    }
    const size_t tbase = isA ? (size_t)b * (KSTEPS * 64)
                             : (size_t)(b - CV_AT) * (KSTEPS * 64);
    const int r0 = tile << 4;

    // step 1: stage (rows >= nrows -> zeros)
    for (int f = t; f < 1024; f += 256) {
        const int row = f >> 6, c4 = f & 63;
        float4 v = make_float4(0.f, 0.f, 0.f, 0.f);
        const int r = r0 + row;
        if (r < nrows) v = *(const float4*)(src + (size_t)r * DD + c4 * 4);
        *(float4*)&raw[row][c4 * 4] = v;
    }
    __syncthreads();

    // step 2: inverse norms; 16 lanes per row
    {
        const int row = t >> 4, seg = t & 15;
        float ss = 0.f;
#pragma unroll
        for (int k = 0; k < 16; ++k) {
            float x = raw[row][k * 16 + seg];
            ss += x * x;
        }
        ss = dpp_sum16(ss);
        if (seg == 0) invn[row] = 1.0f / fmaxf(sqrtf(ss), 1e-8f);
    }
    __syncthreads();

    // step 3: convert + coalesced stores (512 slots, 2 per thread)
    for (int u = t; u < KSTEPS * 64; u += 256) {
        const int ks = u >> 6, sl = u & 63;
        const int rr = sl & 15, kq = sl >> 4;
        const float inv = invn[rr];
        const float* p = &raw[rr][ks * 32 + kq * 8];
        float4 f0 = *(const float4*)p;
        float4 f1 = *(const float4*)(p + 4);
        float xs[8] = {f0.x, f0.y, f0.z, f0.w, f1.x, f1.y, f1.z, f1.w};
        v8hf h;
#pragma unroll
        for (int e = 0; e < 8; ++e) h[e] = (_Float16)(xs[e] * inv);  // RNE f16
        if (isA) Ah_g[tbase + (size_t)ks * 64 + sl] = __builtin_bit_cast(v8ss, h);
        else     Bh_g[tbase + (size_t)ks * 64 + sl] = __builtin_bit_cast(v8ss, h);
    }
}

// ---------------------------------------------------------------------------
// Kernel 2: ONE WAVE = ONE BLOCK = ONE (i,j) PAIR. 16384 blocks of 64
// threads, no LDS, no barriers. SINGLE-PASS f16 MFMA (R7: dropped the
// A-residual pass — error budget ~1e-3 vs 2.25e-3 threshold; halves MFMA,
// cuts traffic 30%, frees 24 VGPR of double-buffer). __launch_bounds__(64,4)
// caps unified regs at 128 -> 4 waves/SIMD static occupancy.
// Register double-buffered fragment loads, tiles pruned by valid lengths.
// Sinkhorn via u/v factorization on P0: row sums via DPP row_ror (16-lane
// groups = C/D rows), col sums via xor-shuffles 16/32, v_rcp_f32 divides,
// exp folded to one fma + v_exp_f32.
// C/D layout: col = lane&15, row = (lane>>4)*4 + reg.
// ---------------------------------------------------------------------------
__global__ __launch_bounds__(64, 4) void pair_kernel(
    const v8ss* __restrict__ Ah_g, const v8ss* __restrict__ Bh_g,
    const int* __restrict__ img_lens, const int* __restrict__ cap_lens,
    float* __restrict__ out)
{
    const int lane = threadIdx.x;
    const int i    = blockIdx.x >> 7;   // 128 consecutive blocks share i (L2 reuse)
    const int j    = blockIdx.x & 127;

    const int nr = img_lens[i];
    const int nc = cap_lens[j];
    const int Ma = (nr + 15) >> 4;
    const int Na = (nc + 15) >> 4;

    const v8ss* Ah_b = Ah_g + (size_t)i * (A_TILES * KSTEPS * 64) + lane;
    const v8ss* Bh_b = Bh_g + (size_t)j * (B_TILES * KSTEPS * 64) + lane;

    v4f acc[3][4];
#pragma unroll
    for (int m = 0; m < 3; ++m)
#pragma unroll
        for (int n = 0; n < 4; ++n) acc[m][n] = (v4f){0.f, 0.f, 0.f, 0.f};

    v8hf ah[2][3], bh[2][4];
    auto load_stage = [&](int ks, int buf) {
#pragma unroll
        for (int m = 0; m < 3; ++m) if (m < Ma)
            ah[buf][m] = __builtin_bit_cast(v8hf, Ah_b[(m * KSTEPS + ks) * 64]);
#pragma unroll
        for (int n = 0; n < 4; ++n) if (n < Na)
            bh[buf][n] = __builtin_bit_cast(v8hf, Bh_b[(n * KSTEPS + ks) * 64]);
    };

    load_stage(0, 0);
#pragma unroll
    for (int ks = 0; ks < KSTEPS; ++ks) {
        const int cur = ks & 1;
        if (ks + 1 < KSTEPS) load_stage(ks + 1, cur ^ 1);
#pragma unroll
        for (int n = 0; n < 4; ++n) if (n < Na)
#pragma unroll
            for (int m = 0; m < 3; ++m) if (m < Ma)
                acc[m][n] = mfma_f16(ah[cur][m], bh[cur][n], acc[m][n]);
    }

    // ---- Sinkhorn via u/v factorization ----
    const int cl = lane & 15;
    const int rq = (lane >> 4) << 2;
    const float inv_nr = 1.0f / (float)nr;
    const float inv_nc = 1.0f / (float)nc;

    float P0[3][4][4];
    float tot = 0.f;
#pragma unroll
    for (int m = 0; m < 3; ++m) if (m < Ma)
#pragma unroll
        for (int n = 0; n < 4; ++n) if (n < Na)
#pragma unroll
            for (int q = 0; q < 4; ++q) {
                const int row = (m << 4) + rq + q;
                const int col = (n << 4) + cl;
                float pv = 0.f;
                if (row < nr && col < nc)
                    pv = fast_exp2(fmaf(acc[m][n][q], EXP2_C1, EXP2_C0));
                P0[m][n][q] = pv;
                tot += pv;
            }
    tot = dpp_sum16(tot);
    tot += __shfl_xor(tot, 16, 64);
    tot += __shfl_xor(tot, 32, 64);
    const float gsc = fast_rcp(tot + EPSF);

    float u[3][4], v[4];
#pragma unroll
    for (int m = 0; m < 3; ++m)
#pragma unroll
        for (int q = 0; q < 4; ++q) u[m][q] = gsc;   // rows with P0=0 harmless
#pragma unroll
    for (int n = 0; n < 4; ++n) v[n] = 1.0f;

#pragma unroll
    for (int it = 0; it < 3; ++it) {
        // row update: t = u[r]*sum_c(P0*v); u *= (1/nr)*rcp(t+EPS)
#pragma unroll
        for (int m = 0; m < 3; ++m) if (m < Ma)
#pragma unroll
            for (int q = 0; q < 4; ++q) {
                float d = 0.f;
#pragma unroll
                for (int n = 0; n < 4; ++n) if (n < Na)
                    d = fmaf(P0[m][n][q], v[n], d);
                d = dpp_sum16(d);
                const float t = fmaf(u[m][q], d, EPSF);
                u[m][q] *= inv_nr * fast_rcp(t);
            }
        // col update: t = v[c]*sum_r(P0*u); v *= (1/nc)*rcp(t+EPS)
#pragma unroll
        for (int n = 0; n < 4; ++n) if (n < Na) {
            float e = 0.f;
#pragma unroll
            for (int m = 0; m < 3; ++m) if (m < Ma)
#pragma unroll
                for (int q = 0; q < 4; ++q)
                    e = fmaf(P0[m][n][q], u[m][q], e);
            e += __shfl_xor(e, 16, 64);
            e += __shfl_xor(e, 32, 64);
            const float t = fmaf(v[n], e, EPSF);
            v[n] *= inv_nc * fast_rcp(t);
        }
    }

    // ---- output: sum(S * P0 * u * v) ----
    float osum = 0.f;
#pragma unroll
    for (int m = 0; m < 3; ++m) if (m < Ma)
#pragma unroll
        for (int n = 0; n < 4; ++n) if (n < Na)
#pragma unroll
            for (int q = 0; q < 4; ++q)
                osum = fmaf(acc[m][n][q], P0[m][n][q] * u[m][q] * v[n], osum);
    osum = dpp_sum16(osum);
    osum += __shfl_xor(osum, 16, 64);
    osum += __shfl_xor(osum, 32, 64);
    if (lane == 0) out[i * BT + j] = osum;
}

extern "C" void kernel_launch(void* const* d_in, const int* in_sizes, int n_in,
                              void* d_out, int out_size, void* d_ws, size_t ws_size,
                              hipStream_t stream) {
    const float* imgs     = (const float*)d_in[0];
    const float* caps     = (const float*)d_in[1];
    const int*   img_lens = (const int*)d_in[2];
    const int*   cap_lens = (const int*)d_in[3];
    float* out = (float*)d_out;

    // workspace layout (7,340,032 bytes total)
    v8ss* Ah_g = (v8ss*)d_ws;
    v8ss* Bh_g = Ah_g + A_SLOTS;

    hipLaunchKernelGGL(convert_kernel, dim3(CV_AT + CV_BT), dim3(256), 0, stream,
                       imgs, caps, Ah_g, Bh_g);
    hipLaunchKernelGGL(pair_kernel, dim3(BI * BT), dim3(64), 0, stream,
                       Ah_g, Bh_g, img_lens, cap_lens, out);
}